// Round 3
// baseline (2300.209 us; speedup 1.0000x reference)
//
#include <hip/hip_runtime.h>

// BeliefPropagation: N=50k, E=1.6M directed edges, q=8, 10 iters.
// R2 change: messages stored in CSR (dst-sorted) order.
//  - gather becomes a contiguous stream (no per-edge indirection / expf)
//  - msg update is edge-parallel: ONE independent random 32B read per thread
//    (msg_old[rev_pos[i]]), contiguous writes; final iter scatters to d_out.
//  - d_out msg region doubles as one ping-pong buffer.

constexpr int Q = 8;
constexpr int NITER = 10;
constexpr int TB = 256;

// ---- one-time: in-degree histogram ----
__global__ void hist_kernel(const int* __restrict__ dst, int* __restrict__ count, int E) {
    int e = blockIdx.x * TB + threadIdx.x;
    if (e < E) atomicAdd(&count[dst[e]], 1);
}

// ---- one-time: exclusive scan (single block, 1024 threads) ----
__global__ void scan_kernel(const int* __restrict__ count, int* __restrict__ row_start, int N) {
    __shared__ int sums[1024];
    int tid = threadIdx.x;
    int chunk = (N + 1023) >> 10;
    int lo = min(tid * chunk, N), hi = min(lo + chunk, N);
    int s = 0;
    for (int i = lo; i < hi; ++i) s += count[i];
    sums[tid] = s;
    __syncthreads();
    for (int off = 1; off < 1024; off <<= 1) {
        int add = (tid >= off) ? sums[tid - off] : 0;
        __syncthreads();
        sums[tid] += add;
        __syncthreads();
    }
    int run = (tid > 0) ? sums[tid - 1] : 0;
    for (int i = lo; i < hi; ++i) { row_start[i] = run; run += count[i]; }
    if (tid == 1023) row_start[N] = sums[1023];
}

// ---- one-time: fill CSR edge-id list + inverse permutation pos[e] ----
__global__ void fill_kernel(const int* __restrict__ dst, int* __restrict__ cursor,
                            int* __restrict__ csr_eid, int* __restrict__ pos, int E) {
    int e = blockIdx.x * TB + threadIdx.x;
    if (e < E) {
        int p = atomicAdd(&cursor[dst[e]], 1);
        csr_eid[p] = e;
        pos[e] = p;
    }
}

// ---- one-time: build CSR-ordered aux arrays + permute msg_init ----
__global__ void aux_kernel(const int* __restrict__ csr_eid,
                           const int* __restrict__ pos,
                           const int* __restrict__ src,
                           const float* __restrict__ edge_attr,
                           const float* __restrict__ beta_p,
                           const float* __restrict__ msg_init,
                           int* __restrict__ src_c,
                           int* __restrict__ rev_pos,
                           float* __restrict__ ew_c,
                           float* __restrict__ msg_c,
                           int E, int M) {
    int i = blockIdx.x * TB + threadIdx.x;
    if (i >= E) return;
    int e = csr_eid[i];
    int re = (e < M) ? (e + M) : (e - M);
    src_c[i] = src[e];
    rev_pos[i] = pos[re];
    float beta = *beta_p;
    ew_c[i] = expf(beta * edge_attr[e]) - 1.0f;
    const float4* mp = reinterpret_cast<const float4*>(msg_init + (size_t)e * Q);
    float4 m0 = mp[0], m1 = mp[1];
    float4* op = reinterpret_cast<float4*>(msg_c + (size_t)i * Q);
    op[0] = m0; op[1] = m1;
}

// ---- bootstrap field: h_accum[k] += deg[n] * psi_init[n,k] ----
__global__ void field_kernel(const float* __restrict__ psi,
                             const int* __restrict__ row_start,
                             float* __restrict__ h_accum, int N) {
    int t = blockIdx.x * TB + threadIdx.x;
    int n = t >> 3, k = t & 7;
    float contrib = 0.f;
    if (n < N) {
        float d = (float)(row_start[n + 1] - row_start[n]);
        contrib = d * psi[(size_t)n * Q + k];
    }
    contrib += __shfl_xor(contrib, 8);
    contrib += __shfl_xor(contrib, 16);
    contrib += __shfl_xor(contrib, 32);
    if ((threadIdx.x & 63) < Q) atomicAdd(&h_accum[threadIdx.x & 7], contrib);
}

// ---- per-iter: nlp[n,k] = sum over CSR segment of log1p(msg_c*ew_c) ----
// 8 lanes per node; contiguous streaming reads of msg_c / ew_c.
// Fused psi + field accumulation.
__global__ void gather_psi_kernel(const float* __restrict__ msg_c,
                                  const float* __restrict__ ew_c,
                                  const int* __restrict__ row_start,
                                  const float* __restrict__ h,
                                  float* __restrict__ nlp,
                                  float* __restrict__ psi_out,
                                  float* __restrict__ h_accum,
                                  int N) {
    int t = blockIdx.x * TB + threadIdx.x;
    int n = t >> 3, k = t & 7;
    float contrib = 0.f;
    if (n < N) {
        int lo = row_start[n], hi = row_start[n + 1];
        float acc = 0.f;
        int i = lo;
        for (; i + 4 <= hi; i += 4) {
            float w0 = ew_c[i],     w1 = ew_c[i + 1];
            float w2 = ew_c[i + 2], w3 = ew_c[i + 3];
            float m0 = msg_c[(size_t)i * Q + k];
            float m1 = msg_c[(size_t)(i + 1) * Q + k];
            float m2 = msg_c[(size_t)(i + 2) * Q + k];
            float m3 = msg_c[(size_t)(i + 3) * Q + k];
            acc += log1pf(m0 * w0) + log1pf(m1 * w1)
                 + log1pf(m2 * w2) + log1pf(m3 * w3);
        }
        for (; i < hi; ++i)
            acc += log1pf(msg_c[(size_t)i * Q + k] * ew_c[i]);
        nlp[(size_t)n * Q + k] = acc;
        float p = expf(h[k] + acc);
        float s = p;
        s += __shfl_xor(s, 1);
        s += __shfl_xor(s, 2);
        s += __shfl_xor(s, 4);
        p /= s;
        psi_out[(size_t)n * Q + k] = p;
        contrib = (float)(hi - lo) * p;
    }
    contrib += __shfl_xor(contrib, 8);
    contrib += __shfl_xor(contrib, 16);
    contrib += __shfl_xor(contrib, 32);
    if ((threadIdx.x & 63) < Q) atomicAdd(&h_accum[threadIdx.x & 7], contrib);
}

// ---- per-iter: new_msg at CSR position i ----
// t_k = exp(h + nlp[src_c[i]] - log1p(msg_old[rev_pos[i]]*ew_c[rev_pos[i]])), norm.
// Contiguous writes; one independent random 32B read per thread.
// Final iter writes to out_msg in ORIGINAL edge order via csr_eid.
__global__ void msg_csr_kernel(const float* __restrict__ msg_old,
                               const float* __restrict__ ew_c,
                               const int* __restrict__ src_c,
                               const int* __restrict__ rev_pos,
                               const float* __restrict__ nlp,
                               const float* __restrict__ h,
                               const int* __restrict__ csr_eid,
                               float* __restrict__ msg_new,
                               int E, int final_iter) {
    int i = blockIdx.x * TB + threadIdx.x;
    if (i >= E) return;
    int rp = rev_pos[i];
    float w = ew_c[rp];
    const float4* mp = reinterpret_cast<const float4*>(msg_old + (size_t)rp * Q);
    float4 m0 = mp[0], m1 = mp[1];
    const float4* np = reinterpret_cast<const float4*>(nlp + (size_t)src_c[i] * Q);
    float4 n0 = np[0], n1 = np[1];
    const float4* hp = reinterpret_cast<const float4*>(h);
    float4 h0 = hp[0], h1 = hp[1];

    float t[Q];
    t[0] = expf(h0.x + n0.x - log1pf(m0.x * w));
    t[1] = expf(h0.y + n0.y - log1pf(m0.y * w));
    t[2] = expf(h0.z + n0.z - log1pf(m0.z * w));
    t[3] = expf(h0.w + n0.w - log1pf(m0.w * w));
    t[4] = expf(h1.x + n1.x - log1pf(m1.x * w));
    t[5] = expf(h1.y + n1.y - log1pf(m1.y * w));
    t[6] = expf(h1.z + n1.z - log1pf(m1.z * w));
    t[7] = expf(h1.w + n1.w - log1pf(m1.w * w));

    float s = 0.f;
#pragma unroll
    for (int k = 0; k < Q; ++k) s += t[k];
    float inv = 1.0f / s;

    size_t oi = final_iter ? (size_t)csr_eid[i] : (size_t)i;
    float4* op = reinterpret_cast<float4*>(msg_new + oi * Q);
    op[0] = make_float4(t[0]*inv, t[1]*inv, t[2]*inv, t[3]*inv);
    op[1] = make_float4(t[4]*inv, t[5]*inv, t[6]*inv, t[7]*inv);
}

// ---- h[k] = -(beta/N) * h_accum[k]; reset h_accum ----
__global__ void finalize_h_kernel(const float* __restrict__ beta_p,
                                  float* __restrict__ h,
                                  float* __restrict__ h_accum,
                                  float invN) {
    int k = threadIdx.x;
    if (k < Q) {
        float beta = *beta_p;
        h[k] = -beta * invN * h_accum[k];
        h_accum[k] = 0.f;
    }
}

extern "C" void kernel_launch(void* const* d_in, const int* in_sizes, int n_in,
                              void* d_out, int out_size, void* d_ws, size_t ws_size,
                              hipStream_t stream) {
    const int*   edge_index = (const int*)d_in[0];
    const float* edge_attr  = (const float*)d_in[1];
    const float* msg_init   = (const float*)d_in[2];
    const float* psi_init   = (const float*)d_in[3];
    const float* beta_p     = (const float*)d_in[4];

    const int E = in_sizes[1];      // 1,600,000
    const int M = E / 2;
    const int N = in_sizes[3] / Q;  // 50,000

    const int* src = edge_index;       // row 0
    const int* dst = edge_index + E;   // row 1

    float* out_msg = (float*)d_out;                      // also ping-pong buffer B
    float* out_psi = (float*)d_out + (size_t)E * Q;

    // workspace carve-up (256B aligned)
    char* ws = (char*)d_ws;
    size_t off = 0;
    auto alloc = [&](size_t bytes) -> void* {
        void* p = (void*)(ws + off);
        off = (off + bytes + 255) & ~(size_t)255;
        return p;
    };
    float* bufA      = (float*)alloc((size_t)E * Q * sizeof(float)); // 51.2 MB
    int*   csr_eid   = (int*)alloc((size_t)E * sizeof(int));         // 6.4 MB
    int*   pos       = (int*)alloc((size_t)E * sizeof(int));         // 6.4 MB
    int*   rev_pos   = (int*)alloc((size_t)E * sizeof(int));         // 6.4 MB
    int*   src_c     = (int*)alloc((size_t)E * sizeof(int));         // 6.4 MB
    float* ew_c      = (float*)alloc((size_t)E * sizeof(float));     // 6.4 MB
    float* nlp       = (float*)alloc((size_t)N * Q * sizeof(float)); // 1.6 MB
    int*   row_start = (int*)alloc((size_t)(N + 1) * sizeof(int));
    float* h         = (float*)alloc(Q * sizeof(float));
    float* h_accum   = (float*)alloc(Q * sizeof(float));
    // setup-only arrays alias the nlp region (nlp first written after setup)
    int* count  = (int*)nlp;
    int* cursor = count + N;
    (void)ws_size;

    const int gE   = (E + TB - 1) / TB;
    const int gOct = (N * Q + TB - 1) / TB;
    const float invN = 1.0f / (float)N;

    // ---- setup: CSR build + permuted arrays + h0 ----
    hipMemsetAsync(count, 0, (size_t)N * sizeof(int), stream);
    hipMemsetAsync(h_accum, 0, Q * sizeof(float), stream);
    hist_kernel<<<gE, TB, 0, stream>>>(dst, count, E);
    scan_kernel<<<1, 1024, 0, stream>>>(count, row_start, N);
    hipMemcpyAsync(cursor, row_start, (size_t)N * sizeof(int),
                   hipMemcpyDeviceToDevice, stream);
    fill_kernel<<<gE, TB, 0, stream>>>(dst, cursor, csr_eid, pos, E);
    // bufB (= out_msg region) receives permuted msg_init
    aux_kernel<<<gE, TB, 0, stream>>>(csr_eid, pos, src, edge_attr, beta_p,
                                      msg_init, src_c, rev_pos, ew_c, out_msg, E, M);
    field_kernel<<<gOct, TB, 0, stream>>>(psi_init, row_start, h_accum, N);
    finalize_h_kernel<<<1, 64, 0, stream>>>(beta_p, h, h_accum, invN);

    // ---- 10 BP iterations (ping-pong: B -> A -> B -> ... ; iter 8 ends in A) ----
    const float* cur = out_msg;   // bufB holds permuted init
    for (int t = 0; t < NITER; ++t) {
        gather_psi_kernel<<<gOct, TB, 0, stream>>>(cur, ew_c, row_start, h,
                                                   nlp, out_psi, h_accum, N);
        int fin = (t == NITER - 1);
        float* wdst = fin ? out_msg : ((t & 1) ? out_msg : bufA);
        msg_csr_kernel<<<gE, TB, 0, stream>>>(cur, ew_c, src_c, rev_pos, nlp, h,
                                              csr_eid, wdst, E, fin);
        finalize_h_kernel<<<1, 64, 0, stream>>>(beta_p, h, h_accum, invN);
        cur = wdst;
    }
}

// Round 4
// 1313.878 us; speedup vs baseline: 1.7507x; 1.7507x over previous
//
#include <hip/hip_runtime.h>

// BeliefPropagation: N=50k, E=1.6M directed edges, q=8, 10 iters.
// R3 changes:
//  - m~ = msg*ew stored (gather needs no ew; msg's random read is ONE 32B line)
//  - nlp' = h + sum log1p  (msg doesn't read h; finalize fused into msg block 0)
//  - CSR build: single atomic pass (p_local) + no-atomic placement pass
//  - gather: wave-per-node (256B contiguous per step)
//  - h accumulation striped across 64*Q floats (no same-line atomic serialization)

constexpr int Q = 8;
constexpr int NITER = 10;
constexpr int TB = 256;
constexpr int NSTRIPE = 64;

// ---- one-time pass1: p_local[e] = atomicAdd(count[dst[e]], 1) ----
__global__ void pass1_kernel(const int* __restrict__ dst, int* __restrict__ count,
                             int* __restrict__ p_local, int E) {
    int e = blockIdx.x * TB + threadIdx.x;
    if (e < E) p_local[e] = atomicAdd(&count[dst[e]], 1);
}

// ---- one-time: exclusive scan (single block, 1024 threads) ----
__global__ void scan_kernel(const int* __restrict__ count, int* __restrict__ row_start, int N) {
    __shared__ int sums[1024];
    int tid = threadIdx.x;
    int chunk = (N + 1023) >> 10;
    int lo = min(tid * chunk, N), hi = min(lo + chunk, N);
    int s = 0;
    for (int i = lo; i < hi; ++i) s += count[i];
    sums[tid] = s;
    __syncthreads();
    for (int off = 1; off < 1024; off <<= 1) {
        int add = (tid >= off) ? sums[tid - off] : 0;
        __syncthreads();
        sums[tid] += add;
        __syncthreads();
    }
    int run = (tid > 0) ? sums[tid - 1] : 0;
    for (int i = lo; i < hi; ++i) { row_start[i] = run; run += count[i]; }
    if (tid == 1023) row_start[N] = sums[1023];
}

// ---- one-time pass2: pos[e] = row_start[dst[e]] + p_local[e]; csr_eid scatter ----
__global__ void pass2_kernel(const int* __restrict__ dst, const int* __restrict__ row_start,
                             const int* __restrict__ p_local, int* __restrict__ pos,
                             int* __restrict__ csr_eid, int E) {
    int e = blockIdx.x * TB + threadIdx.x;
    if (e < E) {
        int p = row_start[dst[e]] + p_local[e];
        pos[e] = p;
        csr_eid[p] = e;
    }
}

// ---- one-time: CSR-ordered aux arrays + m~_init = msg_init * ew ----
__global__ void aux_kernel(const int* __restrict__ csr_eid,
                           const int* __restrict__ pos,
                           const int* __restrict__ src,
                           const float* __restrict__ edge_attr,
                           const float* __restrict__ beta_p,
                           const float* __restrict__ msg_init,
                           int* __restrict__ src_c,
                           int* __restrict__ rev_pos,
                           float* __restrict__ ew_c,
                           float* __restrict__ mt_c,
                           int E, int M) {
    int i = blockIdx.x * TB + threadIdx.x;
    if (i >= E) return;
    int e = csr_eid[i];
    int re = (e < M) ? (e + M) : (e - M);
    src_c[i] = src[e];
    rev_pos[i] = pos[re];
    float beta = *beta_p;
    float w = expf(beta * edge_attr[e]) - 1.0f;
    ew_c[i] = w;
    const float4* mp = reinterpret_cast<const float4*>(msg_init + (size_t)e * Q);
    float4 m0 = mp[0], m1 = mp[1];
    float4* op = reinterpret_cast<float4*>(mt_c + (size_t)i * Q);
    op[0] = make_float4(m0.x * w, m0.y * w, m0.z * w, m0.w * w);
    op[1] = make_float4(m1.x * w, m1.y * w, m1.z * w, m1.w * w);
}

// ---- bootstrap field: striped hacc[s*Q+k] += deg[n] * psi_init[n,k] ----
__global__ void field_kernel(const float* __restrict__ psi,
                             const int* __restrict__ row_start,
                             float* __restrict__ hacc, int N) {
    int t = blockIdx.x * TB + threadIdx.x;
    int n = t >> 3, k = t & 7;
    float contrib = 0.f;
    if (n < N) {
        float d = (float)(row_start[n + 1] - row_start[n]);
        contrib = d * psi[(size_t)n * Q + k];
    }
    contrib += __shfl_xor(contrib, 8);
    contrib += __shfl_xor(contrib, 16);
    contrib += __shfl_xor(contrib, 32);
    if ((threadIdx.x & 63) < Q)
        atomicAdd(&hacc[(blockIdx.x & (NSTRIPE - 1)) * Q + (threadIdx.x & 7)], contrib);
}

// ---- bootstrap h0: h[k] = -(beta/N) * sum_s hacc[s,k]; zero hacc ----
__global__ void h0_kernel(const float* __restrict__ beta_p, float* __restrict__ h,
                          float* __restrict__ hacc, float invN) {
    if (threadIdx.x < Q) {
        float ssum = 0.f;
        for (int s = 0; s < NSTRIPE; ++s) ssum += hacc[s * Q + threadIdx.x];
        h[threadIdx.x] = -(*beta_p) * invN * ssum;
    }
    __syncthreads();
    for (int j = threadIdx.x; j < NSTRIPE * Q; j += TB) hacc[j] = 0.f;
}

// ---- per-iter gather: wave-per-node; nlp'[n,k] = h[k] + sum log1p(m~) ----
// fused psi + striped field accumulation
__global__ void gather_psi_kernel(const float* __restrict__ mt,
                                  const int* __restrict__ row_start,
                                  const float* __restrict__ h,
                                  float* __restrict__ nlp,
                                  float* __restrict__ psi_out,
                                  float* __restrict__ hacc,
                                  int N) {
    __shared__ float accQ[Q];
    int tid = threadIdx.x;
    if (tid < Q) accQ[tid] = 0.f;
    __syncthreads();
    int wave = tid >> 6;
    int lane = tid & 63;
    int es = lane >> 3, k = lane & 7;
    int n = blockIdx.x * 4 + wave;
    if (n < N) {
        int lo = row_start[n], hi = row_start[n + 1];
        float acc = 0.f;
        for (int i = lo + es; i < hi; i += 8)
            acc += log1pf(mt[(size_t)i * Q + k]);
        acc += __shfl_xor(acc, 8);
        acc += __shfl_xor(acc, 16);
        acc += __shfl_xor(acc, 32);
        float nv = h[k] + acc;
        float p = expf(nv);
        float s = p;
        s += __shfl_xor(s, 1);
        s += __shfl_xor(s, 2);
        s += __shfl_xor(s, 4);
        p /= s;
        if (lane < Q) {
            nlp[(size_t)n * Q + k] = nv;
            psi_out[(size_t)n * Q + k] = p;
            atomicAdd(&accQ[k], (float)(hi - lo) * p);
        }
    }
    __syncthreads();
    if (tid < Q)
        atomicAdd(&hacc[(blockIdx.x & (NSTRIPE - 1)) * Q + tid], accQ[tid]);
}

// ---- per-iter msg: t_k = exp(nlp'[src_c[i]] - log1p(m~_old[rev_pos[i]])), norm.
// non-final: write m~_new = norm * ew_c[i] at position i (contiguous)
// final: write plain norm at original edge csr_eid[i] (scatter, once)
// block 0 additionally finalizes h from hacc and resets hacc.
__global__ void msg_kernel(const float* __restrict__ mt_old,
                           const float* __restrict__ ew_c,
                           const int* __restrict__ src_c,
                           const int* __restrict__ rev_pos,
                           const float* __restrict__ nlp,
                           const int* __restrict__ csr_eid,
                           float* __restrict__ msg_out,
                           int E, int final_iter,
                           const float* __restrict__ beta_p,
                           float* __restrict__ h,
                           float* __restrict__ hacc,
                           float invN) {
    int i = blockIdx.x * TB + threadIdx.x;
    if (i < E) {
        int rp = rev_pos[i];
        const float4* mp = reinterpret_cast<const float4*>(mt_old + (size_t)rp * Q);
        float4 m0 = mp[0], m1 = mp[1];
        const float4* np = reinterpret_cast<const float4*>(nlp + (size_t)src_c[i] * Q);
        float4 n0 = np[0], n1 = np[1];

        float t[Q];
        t[0] = expf(n0.x - log1pf(m0.x));
        t[1] = expf(n0.y - log1pf(m0.y));
        t[2] = expf(n0.z - log1pf(m0.z));
        t[3] = expf(n0.w - log1pf(m0.w));
        t[4] = expf(n1.x - log1pf(m1.x));
        t[5] = expf(n1.y - log1pf(m1.y));
        t[6] = expf(n1.z - log1pf(m1.z));
        t[7] = expf(n1.w - log1pf(m1.w));

        float s = 0.f;
#pragma unroll
        for (int k = 0; k < Q; ++k) s += t[k];
        float inv = 1.0f / s;

        if (final_iter) {
            size_t oi = (size_t)csr_eid[i];
            float4* op = reinterpret_cast<float4*>(msg_out + oi * Q);
            op[0] = make_float4(t[0]*inv, t[1]*inv, t[2]*inv, t[3]*inv);
            op[1] = make_float4(t[4]*inv, t[5]*inv, t[6]*inv, t[7]*inv);
        } else {
            float wv = ew_c[i] * inv;
            float4* op = reinterpret_cast<float4*>(msg_out + (size_t)i * Q);
            op[0] = make_float4(t[0]*wv, t[1]*wv, t[2]*wv, t[3]*wv);
            op[1] = make_float4(t[4]*wv, t[5]*wv, t[6]*wv, t[7]*wv);
        }
    }
    // fused h finalize (block 0 only; runs after all gather blocks completed)
    if (blockIdx.x == 0) {
        if (threadIdx.x < Q) {
            float ssum = 0.f;
            for (int s2 = 0; s2 < NSTRIPE; ++s2) ssum += hacc[s2 * Q + threadIdx.x];
            h[threadIdx.x] = -(*beta_p) * invN * ssum;
        }
        __syncthreads();
        for (int j = threadIdx.x; j < NSTRIPE * Q; j += TB) hacc[j] = 0.f;
    }
}

extern "C" void kernel_launch(void* const* d_in, const int* in_sizes, int n_in,
                              void* d_out, int out_size, void* d_ws, size_t ws_size,
                              hipStream_t stream) {
    const int*   edge_index = (const int*)d_in[0];
    const float* edge_attr  = (const float*)d_in[1];
    const float* msg_init   = (const float*)d_in[2];
    const float* psi_init   = (const float*)d_in[3];
    const float* beta_p     = (const float*)d_in[4];

    const int E = in_sizes[1];      // 1,600,000
    const int M = E / 2;
    const int N = in_sizes[3] / Q;  // 50,000

    const int* src = edge_index;       // row 0
    const int* dst = edge_index + E;   // row 1

    float* out_msg = (float*)d_out;                  // doubles as ping-pong buffer B
    float* out_psi = (float*)d_out + (size_t)E * Q;

    // workspace carve-up (256B aligned)
    char* ws = (char*)d_ws;
    size_t off = 0;
    auto alloc = [&](size_t bytes) -> void* {
        void* p = (void*)(ws + off);
        off = (off + bytes + 255) & ~(size_t)255;
        return p;
    };
    float* bufA      = (float*)alloc((size_t)E * Q * sizeof(float)); // 51.2 MB
    int*   csr_eid   = (int*)alloc((size_t)E * sizeof(int));         // 6.4 MB
    int*   pos       = (int*)alloc((size_t)E * sizeof(int));         // 6.4 MB
    int*   p_local   = (int*)alloc((size_t)E * sizeof(int));         // 6.4 MB (reused as rev_pos)
    int*   src_c     = (int*)alloc((size_t)E * sizeof(int));         // 6.4 MB
    float* ew_c      = (float*)alloc((size_t)E * sizeof(float));     // 6.4 MB
    float* nlp       = (float*)alloc((size_t)N * Q * sizeof(float)); // 1.6 MB
    int*   row_start = (int*)alloc((size_t)(N + 1) * sizeof(int));
    float* h         = (float*)alloc(Q * sizeof(float));
    float* hacc      = (float*)alloc(NSTRIPE * Q * sizeof(float));
    int*   rev_pos   = p_local;        // p_local dead after pass2; aux overwrites
    int*   count     = (int*)nlp;      // setup-only alias (nlp first written by gather)
    (void)ws_size;

    const int gE   = (E + TB - 1) / TB;
    const int gOct = (N * Q + TB - 1) / TB;
    const int gW   = (N + 3) / 4;      // wave-per-node gather
    const float invN = 1.0f / (float)N;

    // ---- setup: CSR build + permuted arrays + h0 ----
    hipMemsetAsync(count, 0, (size_t)N * sizeof(int), stream);
    hipMemsetAsync(hacc, 0, NSTRIPE * Q * sizeof(float), stream);
    pass1_kernel<<<gE, TB, 0, stream>>>(dst, count, p_local, E);
    scan_kernel<<<1, 1024, 0, stream>>>(count, row_start, N);
    pass2_kernel<<<gE, TB, 0, stream>>>(dst, row_start, p_local, pos, csr_eid, E);
    aux_kernel<<<gE, TB, 0, stream>>>(csr_eid, pos, src, edge_attr, beta_p,
                                      msg_init, src_c, rev_pos, ew_c, out_msg, E, M);
    field_kernel<<<gOct, TB, 0, stream>>>(psi_init, row_start, hacc, N);
    h0_kernel<<<1, TB, 0, stream>>>(beta_p, h, hacc, invN);

    // ---- 10 BP iterations (cur: B,A,B,A,... ; t=9 reads A, scatters plain to d_out) ----
    const float* cur = out_msg;   // holds m~_init
    for (int t = 0; t < NITER; ++t) {
        gather_psi_kernel<<<gW, TB, 0, stream>>>(cur, row_start, h,
                                                 nlp, out_psi, hacc, N);
        int fin = (t == NITER - 1);
        float* wdst = fin ? out_msg : ((t & 1) ? out_msg : bufA);
        msg_kernel<<<gE, TB, 0, stream>>>(cur, ew_c, src_c, rev_pos, nlp,
                                          csr_eid, wdst, E, fin,
                                          beta_p, h, hacc, invN);
        cur = wdst;
    }
}

// Round 6
// 1017.251 us; speedup vs baseline: 2.2612x; 1.2916x over previous
//
#include <hip/hip_runtime.h>

// BeliefPropagation: N=50k, E=1.6M directed edges, q=8, 10 iters.
// R5 structure: ONE fused kernel per iteration (wave-per-node):
//   phase 1: stream node n's CSR segment of mt=msg*ew, l=log1p(mt) -> LDS,
//            reduce nlp'_n = h + sum l; psi + field accum fused.
//   phase 2: for each incoming edge j of n, the reply message (output position
//            rev_pos[j], which has src = n) is t_k = exp(nlp'_n - l_k(j)),
//            normalized, scatter-written (random 32B WRITE, fire-and-forget).
// Setup: scatter-form aux (all reads contiguous, packed int4 aux per position).

constexpr int Q = 8;
constexpr int NITER = 10;
constexpr int TB = 256;
constexpr int TBW = 512;            // fused kernel block: 8 waves
constexpr int WPB = TBW / 64;       // waves (nodes) per block
constexpr int MAXDEG = 128;         // LDS l-buffer capacity per node (deg>128 recomputes)
constexpr int NSTRIPE = 64;

// ---- one-time: p_local[e] = rank of e among edges with same dst ----
__global__ void pass1_kernel(const int* __restrict__ dst, int* __restrict__ count,
                             int* __restrict__ p_local, int E) {
    int e = blockIdx.x * TB + threadIdx.x;
    if (e < E) p_local[e] = atomicAdd(&count[dst[e]], 1);
}

// ---- one-time: exclusive scan (single block, 1024 threads) ----
__global__ void scan_kernel(const int* __restrict__ count, int* __restrict__ row_start, int N) {
    __shared__ int sums[1024];
    int tid = threadIdx.x;
    int chunk = (N + 1023) >> 10;
    int lo = min(tid * chunk, N), hi = min(lo + chunk, N);
    int s = 0;
    for (int i = lo; i < hi; ++i) s += count[i];
    sums[tid] = s;
    __syncthreads();
    for (int off = 1; off < 1024; off <<= 1) {
        int add = (tid >= off) ? sums[tid - off] : 0;
        __syncthreads();
        sums[tid] += add;
        __syncthreads();
    }
    int run = (tid > 0) ? sums[tid - 1] : 0;
    for (int i = lo; i < hi; ++i) { row_start[i] = run; run += count[i]; }
    if (tid == 1023) row_start[N] = sums[1023];
}

// ---- one-time scatter-aux: contiguous reads, random writes to position p ----
// aux4[p] = {rev_pos, bits(ew_rev), orig_eid, 0}; mt0[p] = msg_init[e]*ew(e)
__global__ void aux_kernel(const int* __restrict__ src, const int* __restrict__ dst,
                           const int* __restrict__ p_local,
                           const int* __restrict__ row_start,
                           const float* __restrict__ edge_attr,
                           const float* __restrict__ beta_p,
                           const float* __restrict__ msg_init,
                           int4* __restrict__ aux4,
                           float* __restrict__ mt0,
                           int E, int M) {
    int e = blockIdx.x * TB + threadIdx.x;
    if (e >= E) return;
    int re = (e < M) ? (e + M) : (e - M);
    float beta = *beta_p;
    float w  = expf(beta * edge_attr[e])  - 1.0f;
    float wr = expf(beta * edge_attr[re]) - 1.0f;
    int p  = row_start[dst[e]] + p_local[e];    // this edge's CSR position
    int rp = row_start[src[e]] + p_local[re];   // reverse edge's CSR position
    aux4[p] = make_int4(rp, __float_as_int(wr), e, 0);
    const float4* mp = reinterpret_cast<const float4*>(msg_init + (size_t)e * Q);
    float4 m0 = mp[0], m1 = mp[1];
    float4* op = reinterpret_cast<float4*>(mt0 + (size_t)p * Q);
    op[0] = make_float4(m0.x * w, m0.y * w, m0.z * w, m0.w * w);
    op[1] = make_float4(m1.x * w, m1.y * w, m1.z * w, m1.w * w);
}

// ---- bootstrap field: striped hacc += deg[n] * psi_init[n,k] ----
__global__ void field_kernel(const float* __restrict__ psi,
                             const int* __restrict__ row_start,
                             float* __restrict__ hacc, int N) {
    int t = blockIdx.x * TB + threadIdx.x;
    int n = t >> 3, k = t & 7;
    float contrib = 0.f;
    if (n < N)
        contrib = (float)(row_start[n + 1] - row_start[n]) * psi[(size_t)n * Q + k];
    contrib += __shfl_xor(contrib, 8);
    contrib += __shfl_xor(contrib, 16);
    contrib += __shfl_xor(contrib, 32);
    if ((threadIdx.x & 63) < Q)
        atomicAdd(&hacc[(blockIdx.x & (NSTRIPE - 1)) * Q + (threadIdx.x & 7)], contrib);
}

// ---- h[k] = -(beta/N) * sum_s hacc[s,k]; zero hacc ----
__global__ void h_fin_kernel(const float* __restrict__ beta_p, float* __restrict__ h,
                             float* __restrict__ hacc, float invN) {
    float s = 0.f;
    if (threadIdx.x < Q)
        for (int j = threadIdx.x; j < NSTRIPE * Q; j += Q) s += hacc[j];
    __syncthreads();
    if (threadIdx.x < Q) h[threadIdx.x] = -(*beta_p) * invN * s;
    for (int j = threadIdx.x; j < NSTRIPE * Q; j += TB) hacc[j] = 0.f;
}

// ---- per-iter fused kernel: wave-per-node ----
template <bool FINAL>
__global__ __launch_bounds__(TBW) void bp_iter_kernel(
    const float* __restrict__ mt_old,
    const int4*  __restrict__ aux4,
    const int*   __restrict__ row_start,
    const float* __restrict__ h,
    float* __restrict__ out,        // FINAL: original-order plain msg; else mt ping buffer
    float* __restrict__ psi_out,
    float* __restrict__ hacc,
    int N, int M) {
    __shared__ float lbuf[WPB][MAXDEG * Q];   // 32 KB
    __shared__ float accQ[Q];
    int tid = threadIdx.x;
    if (tid < Q) accQ[tid] = 0.f;
    __syncthreads();
    int wave = tid >> 6, lane = tid & 63, es = lane >> 3, k = lane & 7;
    int n = blockIdx.x * WPB + wave;
    float contrib = 0.f;
    if (n < N) {
        int lo = row_start[n], hi = row_start[n + 1];
        // phase 1: l = log1p(mt) -> LDS; acc = partial sum
        float acc = 0.f;
        for (int i = lo + es; i < hi; i += 8) {
            float l = log1pf(mt_old[(size_t)i * Q + k]);
            int idx = i - lo;
            if (idx < MAXDEG) lbuf[wave][idx * Q + k] = l;
            acc += l;
        }
        acc += __shfl_xor(acc, 8);
        acc += __shfl_xor(acc, 16);
        acc += __shfl_xor(acc, 32);
        float nlp = h[k] + acc;
        // psi + field contribution (lanes 0..7)
        float pp = expf(nlp);
        float s = pp;
        s += __shfl_xor(s, 1);
        s += __shfl_xor(s, 2);
        s += __shfl_xor(s, 4);
        pp /= s;
        if (lane < Q) {
            psi_out[(size_t)n * Q + k] = pp;
            contrib = (float)(hi - lo) * pp;
        }
        // phase 2: emit reply message for each incoming edge j
        for (int i = lo + es; i < hi; i += 8) {
            int idx = i - lo;
            float l = (idx < MAXDEG) ? lbuf[wave][idx * Q + k]
                                     : log1pf(mt_old[(size_t)i * Q + k]);
            float t = expf(nlp - l);
            float ss = t;
            ss += __shfl_xor(ss, 1);
            ss += __shfl_xor(ss, 2);
            ss += __shfl_xor(ss, 4);
            float inv = 1.0f / ss;
            int4 a = aux4[i];
            if (FINAL) {
                int e = a.z;
                int oe = (e < M) ? (e + M) : (e - M);   // original id of reverse edge
                out[(size_t)oe * Q + k] = t * inv;
            } else {
                out[(size_t)a.x * Q + k] = t * inv * __int_as_float(a.y);
            }
        }
        if (lane < Q) atomicAdd(&accQ[k], contrib);
    }
    __syncthreads();
    if (tid < Q)
        atomicAdd(&hacc[(blockIdx.x & (NSTRIPE - 1)) * Q + tid], accQ[tid]);
}

extern "C" void kernel_launch(void* const* d_in, const int* in_sizes, int n_in,
                              void* d_out, int out_size, void* d_ws, size_t ws_size,
                              hipStream_t stream) {
    const int*   edge_index = (const int*)d_in[0];
    const float* edge_attr  = (const float*)d_in[1];
    const float* msg_init   = (const float*)d_in[2];
    const float* psi_init   = (const float*)d_in[3];
    const float* beta_p     = (const float*)d_in[4];

    const int E = in_sizes[1];      // 1,600,000
    const int M = E / 2;
    const int N = in_sizes[3] / Q;  // 50,000

    const int* src = edge_index;       // row 0
    const int* dst = edge_index + E;   // row 1

    float* out_msg = (float*)d_out;                  // doubles as mt ping buffer B
    float* out_psi = (float*)d_out + (size_t)E * Q;

    // workspace carve-up (256B aligned)
    char* ws = (char*)d_ws;
    size_t off = 0;
    auto alloc = [&](size_t bytes) -> void* {
        void* p = (void*)(ws + off);
        off = (off + bytes + 255) & ~(size_t)255;
        return p;
    };
    float* bufA      = (float*)alloc((size_t)E * Q * sizeof(float)); // 51.2 MB (mt ping A)
    int4*  aux4      = (int4*)alloc((size_t)E * sizeof(int4));       // 25.6 MB
    int*   p_local   = (int*)alloc((size_t)E * sizeof(int));         // 6.4 MB
    int*   row_start = (int*)alloc((size_t)(N + 1) * sizeof(int));
    float* h         = (float*)alloc(Q * sizeof(float));
    float* hacc      = (float*)alloc(NSTRIPE * Q * sizeof(float));
    int*   count     = (int*)bufA;   // setup-only alias (bufA first written at t=0)
    (void)ws_size;

    const int gE   = (E + TB - 1) / TB;
    const int gOct = (N * Q + TB - 1) / TB;
    const int gF   = (N + WPB - 1) / WPB;
    const float invN = 1.0f / (float)N;

    // ---- setup ----
    hipMemsetAsync(count, 0, (size_t)N * sizeof(int), stream);
    hipMemsetAsync(hacc, 0, NSTRIPE * Q * sizeof(float), stream);
    pass1_kernel<<<gE, TB, 0, stream>>>(dst, count, p_local, E);
    scan_kernel<<<1, 1024, 0, stream>>>(count, row_start, N);
    aux_kernel<<<gE, TB, 0, stream>>>(src, dst, p_local, row_start, edge_attr,
                                      beta_p, msg_init, aux4, out_msg, E, M);
    field_kernel<<<gOct, TB, 0, stream>>>(psi_init, row_start, hacc, N);
    h_fin_kernel<<<1, TB, 0, stream>>>(beta_p, h, hacc, invN);

    // ---- 10 iterations: mt ping-pong B->A->B->...; t=9 reads A, writes d_out plain ----
    const float* cur = out_msg;   // holds mt_init
    float*       alt = bufA;
    for (int t = 0; t < NITER - 1; ++t) {
        bp_iter_kernel<false><<<gF, TBW, 0, stream>>>(cur, aux4, row_start, h,
                                                      alt, out_psi, hacc, N, M);
        h_fin_kernel<<<1, TB, 0, stream>>>(beta_p, h, hacc, invN);
        float* tmp = (float*)cur; cur = alt; alt = tmp;
    }
    bp_iter_kernel<true><<<gF, TBW, 0, stream>>>(cur, aux4, row_start, h,
                                                 out_msg, out_psi, hacc, N, M);
}

// Round 12
// 951.808 us; speedup vs baseline: 2.4167x; 1.0688x over previous
//
#include <hip/hip_runtime.h>

// BeliefPropagation: N=50k, E=1.6M directed edges, q=8, 10 iters.
// R7 changes:
//  - pair-form aux (thread per undirected edge): all reads contiguous, no
//    p_local[re] random-read stream, half the threads
//  - h fused into bp_iter via 3-buffer hacc rotation (no h_fin dispatches);
//    each block reduces the 512-float hacc itself (L2-resident)
//  - aux4 staged through LDS during phase 1 (prefetch under log1p stream)
//  - count[] padded to 64B/counter (pass1 atomic line-contention)
//  - psi written only on final iteration

constexpr int Q = 8;
constexpr int NITER = 10;
constexpr int TB = 256;
constexpr int TBW = 512;            // fused kernel block: 8 waves
constexpr int WPB = TBW / 64;       // waves (nodes) per block
constexpr int MAXDEG = 64;          // LDS capacity per node (deg>64 falls back)
constexpr int NSTRIPE = 64;         // NSTRIPE*Q == TBW required
constexpr int CSTRIDE = 16;         // count padding: 64B per counter

// ---- one-time: p_local[e] = rank of e among edges with same dst ----
__global__ void pass1_kernel(const int* __restrict__ dst, int* __restrict__ count,
                             int* __restrict__ p_local, int E) {
    int e = blockIdx.x * TB + threadIdx.x;
    if (e < E) p_local[e] = atomicAdd(&count[(size_t)dst[e] * CSTRIDE], 1);
}

// ---- one-time: exclusive scan over strided counters (single block) ----
__global__ void scan_kernel(const int* __restrict__ count, int* __restrict__ row_start, int N) {
    __shared__ int sums[1024];
    int tid = threadIdx.x;
    int chunk = (N + 1023) >> 10;
    int lo = min(tid * chunk, N), hi = min(lo + chunk, N);
    int s = 0;
    for (int i = lo; i < hi; ++i) s += count[(size_t)i * CSTRIDE];
    sums[tid] = s;
    __syncthreads();
    for (int off = 1; off < 1024; off <<= 1) {
        int add = (tid >= off) ? sums[tid - off] : 0;
        __syncthreads();
        sums[tid] += add;
        __syncthreads();
    }
    int run = (tid > 0) ? sums[tid - 1] : 0;
    for (int i = lo; i < hi; ++i) { row_start[i] = run; run += count[(size_t)i * CSTRIDE]; }
    if (tid == 1023) row_start[N] = sums[1023];
}

// ---- one-time pair-form aux: thread per UNDIRECTED edge e (<M) ----
// handles e (s0->d0) and e+M (d0->s0); all reads contiguous.
// aux4[p] = {rev_pos, bits(ew_rev), orig_eid, 0}; mt0[p] = msg_init*ew
__global__ void aux_kernel(const int* __restrict__ src_row,
                           const int* __restrict__ dst_row,
                           const int* __restrict__ p_local,
                           const int* __restrict__ row_start,
                           const float* __restrict__ edge_attr,
                           const float* __restrict__ beta_p,
                           const float* __restrict__ msg_init,
                           int4* __restrict__ aux4,
                           float* __restrict__ mt0,
                           int M) {
    int e = blockIdx.x * TB + threadIdx.x;
    if (e >= M) return;
    int s0 = src_row[e], d0 = dst_row[e];
    float beta = *beta_p;
    float w  = expf(beta * edge_attr[e])     - 1.0f;   // ew of edge e
    float wr = expf(beta * edge_attr[e + M]) - 1.0f;   // ew of edge e+M
    int p  = row_start[d0] + p_local[e];       // CSR position of e   (dst=d0)
    int rp = row_start[s0] + p_local[e + M];   // CSR position of e+M (dst=s0)
    aux4[p]  = make_int4(rp, __float_as_int(wr), e, 0);
    aux4[rp] = make_int4(p,  __float_as_int(w),  e + M, 0);
    const float4* mp = reinterpret_cast<const float4*>(msg_init + (size_t)e * Q);
    float4 m0 = mp[0], m1 = mp[1];
    float4* op = reinterpret_cast<float4*>(mt0 + (size_t)p * Q);
    op[0] = make_float4(m0.x * w, m0.y * w, m0.z * w, m0.w * w);
    op[1] = make_float4(m1.x * w, m1.y * w, m1.z * w, m1.w * w);
    const float4* mq = reinterpret_cast<const float4*>(msg_init + (size_t)(e + M) * Q);
    float4 r0 = mq[0], r1 = mq[1];
    float4* oq = reinterpret_cast<float4*>(mt0 + (size_t)rp * Q);
    oq[0] = make_float4(r0.x * wr, r0.y * wr, r0.z * wr, r0.w * wr);
    oq[1] = make_float4(r1.x * wr, r1.y * wr, r1.z * wr, r1.w * wr);
}

// ---- bootstrap field: striped hacc0 += deg[n] * psi_init[n,k] ----
__global__ void field_kernel(const float* __restrict__ psi,
                             const int* __restrict__ row_start,
                             float* __restrict__ hacc0, int N) {
    int t = blockIdx.x * TB + threadIdx.x;
    int n = t >> 3, k = t & 7;
    float contrib = 0.f;
    if (n < N)
        contrib = (float)(row_start[n + 1] - row_start[n]) * psi[(size_t)n * Q + k];
    contrib += __shfl_xor(contrib, 8);
    contrib += __shfl_xor(contrib, 16);
    contrib += __shfl_xor(contrib, 32);
    if ((threadIdx.x & 63) < Q)
        atomicAdd(&hacc0[(blockIdx.x & (NSTRIPE - 1)) * Q + (threadIdx.x & 7)], contrib);
}

// ---- per-iter fused kernel: wave-per-node; h derived in-block from hacc_cur ----
template <bool FINAL>
__global__ __launch_bounds__(TBW) void bp_iter_kernel(
    const float* __restrict__ mt_old,
    const int4*  __restrict__ aux4,
    const int*   __restrict__ row_start,
    const float* __restrict__ beta_p,
    const float* __restrict__ hacc_cur,   // read: field sums from prev iter
    float* __restrict__ hacc_nxt,         // accumulate: this iter's field sums
    float* __restrict__ hacc_zer,         // zeroed by block 0 for iter t+2
    float* __restrict__ out,              // FINAL: orig-order plain msg; else mt ping
    float* __restrict__ psi_out,
    int N, int M, float invN) {
    __shared__ float lbuf[WPB][MAXDEG * Q];   // 16 KB
    __shared__ int4  auxbuf[WPB][MAXDEG];     //  8 KB
    __shared__ float hpart[WPB][Q];
    __shared__ float accQ[Q];
    int tid = threadIdx.x;
    int wave = tid >> 6, lane = tid & 63, es = lane >> 3, k = lane & 7;

    // ---- prologue: h[k] = -(beta/N) * sum_s hacc_cur[s,k] (block-local) ----
    float v = hacc_cur[tid];                  // TBW == NSTRIPE*Q
    v += __shfl_xor(v, 8);
    v += __shfl_xor(v, 16);
    v += __shfl_xor(v, 32);
    if (lane < Q) hpart[wave][lane] = v;
    if (tid < Q) accQ[tid] = 0.f;
    if (blockIdx.x == 0) hacc_zer[tid] = 0.f;
    __syncthreads();
    float beta = *beta_p;
    float hk = 0.f;
#pragma unroll
    for (int w2 = 0; w2 < WPB; ++w2) hk += hpart[w2][k];
    hk *= -beta * invN;

    int n = blockIdx.x * WPB + wave;
    float contrib = 0.f;
    if (n < N) {
        int lo = row_start[n], hi = row_start[n + 1];
        // phase 1: stream mt, stage l + aux4 in LDS, reduce nlp
        float acc = 0.f;
        for (int i = lo + es; i < hi; i += 8) {
            int idx = i - lo;
            float mtv = mt_old[(size_t)i * Q + k];
            if (k == 0 && idx < MAXDEG) auxbuf[wave][idx] = aux4[i];
            float l = log1pf(mtv);
            if (idx < MAXDEG) lbuf[wave][idx * Q + k] = l;
            acc += l;
        }
        acc += __shfl_xor(acc, 8);
        acc += __shfl_xor(acc, 16);
        acc += __shfl_xor(acc, 32);
        float nlp = hk + acc;
        // psi + field contribution
        float pp = expf(nlp);
        float s = pp;
        s += __shfl_xor(s, 1);
        s += __shfl_xor(s, 2);
        s += __shfl_xor(s, 4);
        pp /= s;
        if (lane < Q) {
            if (FINAL) psi_out[(size_t)n * Q + k] = pp;
            contrib = (float)(hi - lo) * pp;
        }
        // phase 2: emit reply message per incoming edge
        for (int i = lo + es; i < hi; i += 8) {
            int idx = i - lo;
            float l = (idx < MAXDEG) ? lbuf[wave][idx * Q + k]
                                     : log1pf(mt_old[(size_t)i * Q + k]);
            float t = expf(nlp - l);
            float ss = t;
            ss += __shfl_xor(ss, 1);
            ss += __shfl_xor(ss, 2);
            ss += __shfl_xor(ss, 4);
            float inv = 1.0f / ss;
            int4 a = (idx < MAXDEG) ? auxbuf[wave][idx] : aux4[i];
            if (FINAL) {
                int oe = (a.z < M) ? (a.z + M) : (a.z - M);  // orig id of reverse edge
                out[(size_t)oe * Q + k] = t * inv;
            } else {
                out[(size_t)a.x * Q + k] = t * inv * __int_as_float(a.y);
            }
        }
        if (lane < Q) atomicAdd(&accQ[k], contrib);
    }
    __syncthreads();
    if (tid < Q)
        atomicAdd(&hacc_nxt[(blockIdx.x & (NSTRIPE - 1)) * Q + tid], accQ[tid]);
}

extern "C" void kernel_launch(void* const* d_in, const int* in_sizes, int n_in,
                              void* d_out, int out_size, void* d_ws, size_t ws_size,
                              hipStream_t stream) {
    const int*   edge_index = (const int*)d_in[0];
    const float* edge_attr  = (const float*)d_in[1];
    const float* msg_init   = (const float*)d_in[2];
    const float* psi_init   = (const float*)d_in[3];
    const float* beta_p     = (const float*)d_in[4];

    const int E = in_sizes[1];      // 1,600,000
    const int M = E / 2;
    const int N = in_sizes[3] / Q;  // 50,000

    const int* src = edge_index;       // row 0
    const int* dst = edge_index + E;   // row 1

    float* out_msg = (float*)d_out;                  // doubles as mt ping buffer B
    float* out_psi = (float*)d_out + (size_t)E * Q;

    // workspace carve-up (256B aligned)
    char* ws = (char*)d_ws;
    size_t off = 0;
    auto alloc = [&](size_t bytes) -> void* {
        void* p = (void*)(ws + off);
        off = (off + bytes + 255) & ~(size_t)255;
        return p;
    };
    float* bufA      = (float*)alloc((size_t)E * Q * sizeof(float));       // 51.2 MB
    int4*  aux4      = (int4*)alloc((size_t)E * sizeof(int4));             // 25.6 MB
    int*   p_local   = (int*)alloc((size_t)E * sizeof(int));               // 6.4 MB
    int*   count     = (int*)alloc((size_t)N * CSTRIDE * sizeof(int));     // 3.2 MB
    int*   row_start = (int*)alloc((size_t)(N + 1) * sizeof(int));
    float* hacc3     = (float*)alloc(3 * NSTRIPE * Q * sizeof(float));     // 6 KB
    (void)ws_size;

    const int gE   = (E + TB - 1) / TB;
    const int gM   = (M + TB - 1) / TB;
    const int gOct = (N * Q + TB - 1) / TB;
    const int gF   = (N + WPB - 1) / WPB;
    const float invN = 1.0f / (float)N;

    // ---- setup ----
    hipMemsetAsync(count, 0, (size_t)N * CSTRIDE * sizeof(int), stream);
    hipMemsetAsync(hacc3, 0, 3 * NSTRIPE * Q * sizeof(float), stream);
    pass1_kernel<<<gE, TB, 0, stream>>>(dst, count, p_local, E);
    scan_kernel<<<1, 1024, 0, stream>>>(count, row_start, N);
    aux_kernel<<<gM, TB, 0, stream>>>(src, dst, p_local, row_start, edge_attr,
                                      beta_p, msg_init, aux4, out_msg, M);
    field_kernel<<<gOct, TB, 0, stream>>>(psi_init, row_start, hacc3, N);

    // ---- 10 iterations; hacc rotation: read t%3, accumulate (t+1)%3, zero (t+2)%3 ----
    const float* cur = out_msg;   // holds mt_init
    float*       alt = bufA;
    for (int t = 0; t < NITER - 1; ++t) {
        bp_iter_kernel<false><<<gF, TBW, 0, stream>>>(
            cur, aux4, row_start, beta_p,
            hacc3 + (size_t)(t % 3) * NSTRIPE * Q,
            hacc3 + (size_t)((t + 1) % 3) * NSTRIPE * Q,
            hacc3 + (size_t)((t + 2) % 3) * NSTRIPE * Q,
            alt, out_psi, N, M, invN);
        float* tmp = (float*)cur; cur = alt; alt = tmp;
    }
    {
        int t = NITER - 1;
        bp_iter_kernel<true><<<gF, TBW, 0, stream>>>(
            cur, aux4, row_start, beta_p,
            hacc3 + (size_t)(t % 3) * NSTRIPE * Q,
            hacc3 + (size_t)((t + 1) % 3) * NSTRIPE * Q,
            hacc3 + (size_t)((t + 2) % 3) * NSTRIPE * Q,
            out_msg, out_psi, N, M, invN);
    }
}

// Round 13
// 848.273 us; speedup vs baseline: 2.7116x; 1.1221x over previous
//
#include <hip/hip_runtime.h>

// BeliefPropagation: N=50k, E=1.6M directed edges, q=8, 10 iters.
// R8 change (single-variable): replace the 113us single-block latency-bound
// scan (1024 threads x 49-deep strided dependent loads) with a hierarchical
// 3-kernel scan: 49-block parallel block-scan -> 1-wave scan of block sums
// -> offset add. Everything else identical to R7.

constexpr int Q = 8;
constexpr int NITER = 10;
constexpr int TB = 256;
constexpr int TBW = 512;            // fused kernel block: 8 waves
constexpr int WPB = TBW / 64;       // waves (nodes) per block
constexpr int MAXDEG = 64;          // LDS capacity per node (deg>64 falls back)
constexpr int NSTRIPE = 64;         // NSTRIPE*Q == TBW required
constexpr int CSTRIDE = 16;         // count padding: 64B per counter
constexpr int SCB = 1024;           // counters per scan block

// ---- one-time: p_local[e] = rank of e among edges with same dst ----
__global__ void pass1_kernel(const int* __restrict__ dst, int* __restrict__ count,
                             int* __restrict__ p_local, int E) {
    int e = blockIdx.x * TB + threadIdx.x;
    if (e < E) p_local[e] = atomicAdd(&count[(size_t)dst[e] * CSTRIDE], 1);
}

// ---- one-time scanA: per-block exclusive scan of 1024 strided counters ----
__global__ void scanA_kernel(const int* __restrict__ count, int* __restrict__ row_start,
                             int* __restrict__ blocksum, int N) {
    __shared__ int buf[SCB];
    int tid = threadIdx.x;
    int gi = blockIdx.x * SCB + tid;
    int v = (gi < N) ? count[(size_t)gi * CSTRIDE] : 0;
    buf[tid] = v;
    __syncthreads();
    for (int off = 1; off < SCB; off <<= 1) {
        int add = (tid >= off) ? buf[tid - off] : 0;
        __syncthreads();
        buf[tid] += add;
        __syncthreads();
    }
    if (gi < N) row_start[gi] = buf[tid] - v;           // local exclusive
    if (tid == SCB - 1) blocksum[blockIdx.x] = buf[tid]; // block total
}

// ---- one-time scanB: 1 wave scans block sums -> exclusive offsets; total -> row_start[N] ----
__global__ void scanB_kernel(int* __restrict__ blocksum, int* __restrict__ row_start,
                             int nblk, int N) {
    int tid = threadIdx.x;   // 64 threads, one wave
    int orig = (tid < nblk) ? blocksum[tid] : 0;
    int v = orig;
    for (int off = 1; off < 64; off <<= 1) {
        int u = __shfl_up(v, off);
        if (tid >= off) v += u;
    }
    if (tid < nblk) blocksum[tid] = v - orig;  // exclusive offset
    if (tid == nblk - 1) row_start[N] = v;     // grand total = E
}

// ---- one-time scanC: add block offsets ----
__global__ void scanC_kernel(int* __restrict__ row_start, const int* __restrict__ blocksum,
                             int N) {
    int gi = blockIdx.x * SCB + threadIdx.x;
    if (gi < N) row_start[gi] += blocksum[blockIdx.x];
}

// ---- one-time pair-form aux: thread per UNDIRECTED edge e (<M) ----
// handles e (s0->d0) and e+M (d0->s0); all reads contiguous.
// aux4[p] = {rev_pos, bits(ew_rev), orig_eid, 0}; mt0[p] = msg_init*ew
__global__ void aux_kernel(const int* __restrict__ src_row,
                           const int* __restrict__ dst_row,
                           const int* __restrict__ p_local,
                           const int* __restrict__ row_start,
                           const float* __restrict__ edge_attr,
                           const float* __restrict__ beta_p,
                           const float* __restrict__ msg_init,
                           int4* __restrict__ aux4,
                           float* __restrict__ mt0,
                           int M) {
    int e = blockIdx.x * TB + threadIdx.x;
    if (e >= M) return;
    int s0 = src_row[e], d0 = dst_row[e];
    float beta = *beta_p;
    float w  = expf(beta * edge_attr[e])     - 1.0f;   // ew of edge e
    float wr = expf(beta * edge_attr[e + M]) - 1.0f;   // ew of edge e+M
    int p  = row_start[d0] + p_local[e];       // CSR position of e   (dst=d0)
    int rp = row_start[s0] + p_local[e + M];   // CSR position of e+M (dst=s0)
    aux4[p]  = make_int4(rp, __float_as_int(wr), e, 0);
    aux4[rp] = make_int4(p,  __float_as_int(w),  e + M, 0);
    const float4* mp = reinterpret_cast<const float4*>(msg_init + (size_t)e * Q);
    float4 m0 = mp[0], m1 = mp[1];
    float4* op = reinterpret_cast<float4*>(mt0 + (size_t)p * Q);
    op[0] = make_float4(m0.x * w, m0.y * w, m0.z * w, m0.w * w);
    op[1] = make_float4(m1.x * w, m1.y * w, m1.z * w, m1.w * w);
    const float4* mq = reinterpret_cast<const float4*>(msg_init + (size_t)(e + M) * Q);
    float4 r0 = mq[0], r1 = mq[1];
    float4* oq = reinterpret_cast<float4*>(mt0 + (size_t)rp * Q);
    oq[0] = make_float4(r0.x * wr, r0.y * wr, r0.z * wr, r0.w * wr);
    oq[1] = make_float4(r1.x * wr, r1.y * wr, r1.z * wr, r1.w * wr);
}

// ---- bootstrap field: striped hacc0 += deg[n] * psi_init[n,k] ----
__global__ void field_kernel(const float* __restrict__ psi,
                             const int* __restrict__ row_start,
                             float* __restrict__ hacc0, int N) {
    int t = blockIdx.x * TB + threadIdx.x;
    int n = t >> 3, k = t & 7;
    float contrib = 0.f;
    if (n < N)
        contrib = (float)(row_start[n + 1] - row_start[n]) * psi[(size_t)n * Q + k];
    contrib += __shfl_xor(contrib, 8);
    contrib += __shfl_xor(contrib, 16);
    contrib += __shfl_xor(contrib, 32);
    if ((threadIdx.x & 63) < Q)
        atomicAdd(&hacc0[(blockIdx.x & (NSTRIPE - 1)) * Q + (threadIdx.x & 7)], contrib);
}

// ---- per-iter fused kernel: wave-per-node; h derived in-block from hacc_cur ----
template <bool FINAL>
__global__ __launch_bounds__(TBW) void bp_iter_kernel(
    const float* __restrict__ mt_old,
    const int4*  __restrict__ aux4,
    const int*   __restrict__ row_start,
    const float* __restrict__ beta_p,
    const float* __restrict__ hacc_cur,   // read: field sums from prev iter
    float* __restrict__ hacc_nxt,         // accumulate: this iter's field sums
    float* __restrict__ hacc_zer,         // zeroed by block 0 for iter t+2
    float* __restrict__ out,              // FINAL: orig-order plain msg; else mt ping
    float* __restrict__ psi_out,
    int N, int M, float invN) {
    __shared__ float lbuf[WPB][MAXDEG * Q];   // 16 KB
    __shared__ int4  auxbuf[WPB][MAXDEG];     //  8 KB
    __shared__ float hpart[WPB][Q];
    __shared__ float accQ[Q];
    int tid = threadIdx.x;
    int wave = tid >> 6, lane = tid & 63, es = lane >> 3, k = lane & 7;

    // ---- prologue: h[k] = -(beta/N) * sum_s hacc_cur[s,k] (block-local) ----
    float v = hacc_cur[tid];                  // TBW == NSTRIPE*Q
    v += __shfl_xor(v, 8);
    v += __shfl_xor(v, 16);
    v += __shfl_xor(v, 32);
    if (lane < Q) hpart[wave][lane] = v;
    if (tid < Q) accQ[tid] = 0.f;
    if (blockIdx.x == 0) hacc_zer[tid] = 0.f;
    __syncthreads();
    float beta = *beta_p;
    float hk = 0.f;
#pragma unroll
    for (int w2 = 0; w2 < WPB; ++w2) hk += hpart[w2][k];
    hk *= -beta * invN;

    int n = blockIdx.x * WPB + wave;
    float contrib = 0.f;
    if (n < N) {
        int lo = row_start[n], hi = row_start[n + 1];
        // phase 1: stream mt, stage l + aux4 in LDS, reduce nlp
        float acc = 0.f;
        for (int i = lo + es; i < hi; i += 8) {
            int idx = i - lo;
            float mtv = mt_old[(size_t)i * Q + k];
            if (k == 0 && idx < MAXDEG) auxbuf[wave][idx] = aux4[i];
            float l = log1pf(mtv);
            if (idx < MAXDEG) lbuf[wave][idx * Q + k] = l;
            acc += l;
        }
        acc += __shfl_xor(acc, 8);
        acc += __shfl_xor(acc, 16);
        acc += __shfl_xor(acc, 32);
        float nlp = hk + acc;
        // psi + field contribution
        float pp = expf(nlp);
        float s = pp;
        s += __shfl_xor(s, 1);
        s += __shfl_xor(s, 2);
        s += __shfl_xor(s, 4);
        pp /= s;
        if (lane < Q) {
            if (FINAL) psi_out[(size_t)n * Q + k] = pp;
            contrib = (float)(hi - lo) * pp;
        }
        // phase 2: emit reply message per incoming edge
        for (int i = lo + es; i < hi; i += 8) {
            int idx = i - lo;
            float l = (idx < MAXDEG) ? lbuf[wave][idx * Q + k]
                                     : log1pf(mt_old[(size_t)i * Q + k]);
            float t = expf(nlp - l);
            float ss = t;
            ss += __shfl_xor(ss, 1);
            ss += __shfl_xor(ss, 2);
            ss += __shfl_xor(ss, 4);
            float inv = 1.0f / ss;
            int4 a = (idx < MAXDEG) ? auxbuf[wave][idx] : aux4[i];
            if (FINAL) {
                int oe = (a.z < M) ? (a.z + M) : (a.z - M);  // orig id of reverse edge
                out[(size_t)oe * Q + k] = t * inv;
            } else {
                out[(size_t)a.x * Q + k] = t * inv * __int_as_float(a.y);
            }
        }
        if (lane < Q) atomicAdd(&accQ[k], contrib);
    }
    __syncthreads();
    if (tid < Q)
        atomicAdd(&hacc_nxt[(blockIdx.x & (NSTRIPE - 1)) * Q + tid], accQ[tid]);
}

extern "C" void kernel_launch(void* const* d_in, const int* in_sizes, int n_in,
                              void* d_out, int out_size, void* d_ws, size_t ws_size,
                              hipStream_t stream) {
    const int*   edge_index = (const int*)d_in[0];
    const float* edge_attr  = (const float*)d_in[1];
    const float* msg_init   = (const float*)d_in[2];
    const float* psi_init   = (const float*)d_in[3];
    const float* beta_p     = (const float*)d_in[4];

    const int E = in_sizes[1];      // 1,600,000
    const int M = E / 2;
    const int N = in_sizes[3] / Q;  // 50,000

    const int* src = edge_index;       // row 0
    const int* dst = edge_index + E;   // row 1

    float* out_msg = (float*)d_out;                  // doubles as mt ping buffer B
    float* out_psi = (float*)d_out + (size_t)E * Q;

    // workspace carve-up (256B aligned)
    char* ws = (char*)d_ws;
    size_t off = 0;
    auto alloc = [&](size_t bytes) -> void* {
        void* p = (void*)(ws + off);
        off = (off + bytes + 255) & ~(size_t)255;
        return p;
    };
    float* bufA      = (float*)alloc((size_t)E * Q * sizeof(float));       // 51.2 MB
    int4*  aux4      = (int4*)alloc((size_t)E * sizeof(int4));             // 25.6 MB
    int*   p_local   = (int*)alloc((size_t)E * sizeof(int));               // 6.4 MB
    int*   count     = (int*)alloc((size_t)N * CSTRIDE * sizeof(int));     // 3.2 MB
    int*   row_start = (int*)alloc((size_t)(N + 1) * sizeof(int));
    int*   blocksum  = (int*)alloc(64 * sizeof(int));
    float* hacc3     = (float*)alloc(3 * NSTRIPE * Q * sizeof(float));     // 6 KB
    (void)ws_size;

    const int gE   = (E + TB - 1) / TB;
    const int gM   = (M + TB - 1) / TB;
    const int gOct = (N * Q + TB - 1) / TB;
    const int gF   = (N + WPB - 1) / WPB;
    const int nblk = (N + SCB - 1) / SCB;   // 49
    const float invN = 1.0f / (float)N;

    // ---- setup ----
    hipMemsetAsync(count, 0, (size_t)N * CSTRIDE * sizeof(int), stream);
    hipMemsetAsync(hacc3, 0, 3 * NSTRIPE * Q * sizeof(float), stream);
    pass1_kernel<<<gE, TB, 0, stream>>>(dst, count, p_local, E);
    scanA_kernel<<<nblk, SCB, 0, stream>>>(count, row_start, blocksum, N);
    scanB_kernel<<<1, 64, 0, stream>>>(blocksum, row_start, nblk, N);
    scanC_kernel<<<nblk, SCB, 0, stream>>>(row_start, blocksum, N);
    aux_kernel<<<gM, TB, 0, stream>>>(src, dst, p_local, row_start, edge_attr,
                                      beta_p, msg_init, aux4, out_msg, M);
    field_kernel<<<gOct, TB, 0, stream>>>(psi_init, row_start, hacc3, N);

    // ---- 10 iterations; hacc rotation: read t%3, accumulate (t+1)%3, zero (t+2)%3 ----
    const float* cur = out_msg;   // holds mt_init
    float*       alt = bufA;
    for (int t = 0; t < NITER - 1; ++t) {
        bp_iter_kernel<false><<<gF, TBW, 0, stream>>>(
            cur, aux4, row_start, beta_p,
            hacc3 + (size_t)(t % 3) * NSTRIPE * Q,
            hacc3 + (size_t)((t + 1) % 3) * NSTRIPE * Q,
            hacc3 + (size_t)((t + 2) % 3) * NSTRIPE * Q,
            alt, out_psi, N, M, invN);
        float* tmp = (float*)cur; cur = alt; alt = tmp;
    }
    {
        int t = NITER - 1;
        bp_iter_kernel<true><<<gF, TBW, 0, stream>>>(
            cur, aux4, row_start, beta_p,
            hacc3 + (size_t)(t % 3) * NSTRIPE * Q,
            hacc3 + (size_t)((t + 1) % 3) * NSTRIPE * Q,
            hacc3 + (size_t)((t + 2) % 3) * NSTRIPE * Q,
            out_msg, out_psi, N, M, invN);
    }
}